// Round 4
// baseline (49.470 us; speedup 1.0000x reference)
//
#include <hip/hip_runtime.h>

// YOLO layer: input [B=16, A*C=255, G=76, G=76] f32, anchors [3,2] f32.
// Output [B, A*G*G=17328, C=85] f32.
//   c=0: (sigmoid+gx)*8, c=1: (sigmoid+gy)*8, c=2: exp*aw, c=3: exp*ah,
//   c>=4: sigmoid   (anchor/stride scaling folded: (e^w * aw/8)*8 == e^w*aw)
//
// Persistent grid-stride blocks + register pipeline with RAW barriers:
//   __syncthreads() would emit s_waitcnt vmcnt(0) before s_barrier, draining
//   the tile g+GRID prefetch loads (the m97-ceiling stall). LDS reuse only
//   requires lgkmcnt(0) at the barriers, so we use
//   asm("s_waitcnt lgkmcnt(0)") + __builtin_amdgcn_s_barrier() and let the
//   prefetch stay in flight across the store phase (T4: counted vmcnt only
//   where v[] is consumed, inserted automatically by the compiler).

#define GDIM 76
#define GG 5776            // 76*76 (divisible by 4)
#define NA 3
#define NCH 85
#define TILE 64            // spatial positions per block-tile
#define THREADS 256        // 4 waves
#define LOAD_UNITS (NCH * (TILE / 4))  // 1360 float4 units per tile
#define LITERS 6                       // ceil(1360/256)
#define TPB 91                         // tiles per (b,a): ceil(5776/64)
#define NT (TPB * NA * 16)             // 4368 total tiles
#define GRID 1792                      // 7 blocks/CU * 256 CUs (LDS cap)

// LDS-reuse barrier: waits LDS ops only; global loads/stores stay in flight.
#define LDS_BARRIER() do {                                   \
    asm volatile("s_waitcnt lgkmcnt(0)" ::: "memory");       \
    __builtin_amdgcn_s_barrier();                            \
} while (0)

__global__ __launch_bounds__(THREADS) void yolo_kernel(
    const float* __restrict__ in, const float* __restrict__ anchors,
    float* __restrict__ out)
{
    __shared__ float lds[TILE * NCH];   // 21760 B -> 7 blocks/CU

    const int t = threadIdx.x;

    // hoist all 3 anchor pairs once
    const float aw0 = anchors[0], ah0 = anchors[1];
    const float aw1 = anchors[2], ah1 = anchors[3];
    const float aw2 = anchors[4], ah2 = anchors[5];

    float4 v[LITERS];

    auto load_tile = [&](int g) {
        int ba   = g / TPB;
        int tile = g - ba * TPB;
        int s0   = tile * TILE;
        const float* inb = in + (long)ba * (NCH * GG);
        #pragma unroll
        for (int i = 0; i < LITERS; ++i) {
            int idx = t + i * THREADS;
            int c   = idx >> 4;
            int q   = idx & 15;
            int pos = s0 + q * 4;
            if (idx < LOAD_UNITS && pos < GG)
                v[i] = *reinterpret_cast<const float4*>(&inb[(long)c * GG + pos]);
        }
    };

    auto transform_write = [&](int g) {
        int ba   = g / TPB;
        int tile = g - ba * TPB;
        int a    = ba % NA;
        int s0   = tile * TILE;
        float aw = (a == 0) ? aw0 : (a == 1) ? aw1 : aw2;
        float ah = (a == 0) ? ah0 : (a == 1) ? ah1 : ah2;
        #pragma unroll
        for (int i = 0; i < LITERS; ++i) {
            int idx = t + i * THREADS;
            int c   = idx >> 4;
            int q   = idx & 15;
            int pos = s0 + q * 4;
            if (idx < LOAD_UNITS && pos < GG) {
                float r[4] = {v[i].x, v[i].y, v[i].z, v[i].w};
                if (c == 0) {
                    #pragma unroll
                    for (int k = 0; k < 4; ++k) {
                        int p = pos + k;
                        float gx = (float)(p - (p / GDIM) * GDIM);
                        r[k] = (1.0f / (1.0f + expf(-r[k])) + gx) * 8.0f;
                    }
                } else if (c == 1) {
                    #pragma unroll
                    for (int k = 0; k < 4; ++k) {
                        int p = pos + k;
                        float gy = (float)(p / GDIM);
                        r[k] = (1.0f / (1.0f + expf(-r[k])) + gy) * 8.0f;
                    }
                } else if (c == 2) {
                    #pragma unroll
                    for (int k = 0; k < 4; ++k) r[k] = expf(r[k]) * aw;
                } else if (c == 3) {
                    #pragma unroll
                    for (int k = 0; k < 4; ++k) r[k] = expf(r[k]) * ah;
                } else {
                    #pragma unroll
                    for (int k = 0; k < 4; ++k) r[k] = 1.0f / (1.0f + expf(-r[k]));
                }
                #pragma unroll
                for (int k = 0; k < 4; ++k)
                    lds[(q * 4 + k) * NCH + c] = r[k];
            }
        }
    };

    auto store_tile = [&](int g) {
        int ba    = g / TPB;
        int tile  = g - ba * TPB;
        int s0    = tile * TILE;
        int valid = (GG - s0 < TILE) ? (GG - s0) : TILE;  // 64 or 16
        int n4    = valid * NCH / 4;                       // 1360 or 340
        float4* __restrict__ outv =
            reinterpret_cast<float4*>(out + ((long)ba * GG + s0) * NCH);
        const float4* ldsv = reinterpret_cast<const float4*>(lds);
        #pragma unroll
        for (int i = 0; i < LITERS; ++i) {
            int f4 = t + i * THREADS;
            if (f4 < n4)
                outv[f4] = ldsv[f4];
        }
    };

    int g = blockIdx.x;
    load_tile(g);                       // prologue (every block has >=2 tiles)
    for (; g < NT; g += GRID) {
        transform_write(g);             // waits vmcnt for v[] only, fills LDS
        LDS_BARRIER();                  // ds_writes visible; prefetch in flight
        int gn = g + GRID;
        if (gn < NT) load_tile(gn);     // issue next-tile loads
        store_tile(g);                  // ds_read_b128 -> global_store_dwordx4
        LDS_BARRIER();                  // ds_reads done; LDS reusable
    }
}

extern "C" void kernel_launch(void* const* d_in, const int* in_sizes, int n_in,
                              void* d_out, int out_size, void* d_ws, size_t ws_size,
                              hipStream_t stream) {
    const float* pred    = (const float*)d_in[0];
    const float* anchors = (const float*)d_in[1];
    float* out           = (float*)d_out;

    yolo_kernel<<<dim3(GRID), dim3(THREADS), 0, stream>>>(pred, anchors, out);
}